// Round 4
// baseline (383.986 us; speedup 1.0000x reference)
//
#include <hip/hip_runtime.h>
#include <hip/hip_bf16.h>
#include <cstdint>

typedef unsigned int u32;
typedef unsigned long long u64;

#define ANUM 131072
#define BATCH 4
#define PRE 3000
#define CAP 4096
#define NW 47          /* ceil(3000/64) */
#define MROW 48        /* padded u64 words per mask row (16B-aligned stripes) */
#define MAXOUT 1000
#define NBUCK 64       /* candidate buckets per batch */
#define BCAP 256       /* slots per bucket (lambda~52, overflow impossible) */

/* ---- workspace layout (bytes) ----
 * cand aliases hist1 (hist1 dead after k_sel1, cand written by k_compact later)
 */
#define OFF_CAND  0ul                  /* u64[B][NBUCK][BCAP] = 512KB (aliases hist1) */
#define OFF_HIST1 0ul                  /* u32[B][65536] = 1MB */
#define OFF_HIST2 1048576ul            /* u32[B][65536] = 1MB */
#define OFF_INFO  2097152ul            /* u32[256]: [0..3]=b16 [4..7]=c_above [8..11]=T [16..19]=keptcnt */
#define OFF_BCNT  2098176ul            /* u32[B*NBUCK*16] (64B-padded counters) = 16KB */
#define OFF_ORDER 2114560ul            /* u32[B][PRE] */
#define OFF_SCORE 2162560ul            /* f32[B][PRE] */
#define OFF_BOXES 2210560ul            /* f32[B][PRE][6] */
#define OFF_MASKS 2498560ul            /* u64[B][PRE][MROW] = 4608000 (row-major, padded) */
#define OFF_KEPT  7106560ul            /* u32[B][PRE] -> end 7154560 (< 7185280 proven cap) */
#define MEMSET_BYTES 2114560ul         /* hists + info + bcnt */

__device__ __forceinline__ u32 score_key(float f) {
  u32 u = __float_as_uint(f);
  return (u & 0x80000000u) ? ~u : (u | 0x80000000u);
}

/* ---------- 1. histogram of top 16 bits ---------- */
__global__ void k_hist1(const float* __restrict__ scores, u32* __restrict__ hist) {
  int t = blockIdx.x * blockDim.x + threadIdx.x;      /* 0 .. B*ANUM-1 */
  int b = t >> 17;
  u32 key = score_key(scores[t]);
  atomicAdd(&hist[(b << 16) + (key >> 16)], 1u);
}

/* ---------- 2. find high-16 bin crossing rank 3000 ---------- */
__global__ void k_sel1(const u32* __restrict__ hist, u32* __restrict__ info) {
  int b = blockIdx.x, tid = threadIdx.x;              /* 256 threads */
  __shared__ u32 part[256];
  const u32* h = hist + (b << 16);
  u32 s = 0;
  for (int r = tid * 256; r < tid * 256 + 256; ++r) s += h[65535 - r];
  part[tid] = s;
  __syncthreads();
  if (tid == 0) {
    u32 c = 0; int tstar = 0; u32 cb = 0;
    for (int t = 0; t < 256; ++t) {
      if (c + part[t] >= PRE) { tstar = t; cb = c; break; }
      c += part[t];
    }
    u32 cc = cb; int b16 = 0;
    for (int r = tstar * 256; r < 65536; ++r) {
      u32 cnt = h[65535 - r];
      if (cc + cnt >= PRE) { b16 = 65535 - r; break; }
      cc += cnt;
    }
    info[b] = (u32)b16;
    info[4 + b] = cc;                                  /* count strictly above bin */
  }
}

/* ---------- 3. histogram of low 16 bits within the boundary bin ---------- */
__global__ void k_hist2(const float* __restrict__ scores, const u32* __restrict__ info,
                        u32* __restrict__ hist2) {
  int t = blockIdx.x * blockDim.x + threadIdx.x;
  int b = t >> 17;
  u32 key = score_key(scores[t]);
  if ((key >> 16) == info[b])
    atomicAdd(&hist2[(b << 16) + (key & 0xFFFFu)], 1u);
}

/* ---------- 4. exact threshold key T ---------- */
__global__ void k_sel2(const u32* __restrict__ hist2, u32* __restrict__ info) {
  int b = blockIdx.x, tid = threadIdx.x;
  __shared__ u32 part[256];
  const u32* h = hist2 + (b << 16);
  u32 s = 0;
  for (int r = tid * 256; r < tid * 256 + 256; ++r) s += h[65535 - r];
  part[tid] = s;
  __syncthreads();
  if (tid == 0) {
    int target = PRE - (int)info[4 + b];               /* >=1 */
    u32 c = 0; int tstar = 0; u32 cb = 0;
    for (int t = 0; t < 256; ++t) {
      if ((int)(c + part[t]) >= target) { tstar = t; cb = c; break; }
      c += part[t];
    }
    u32 cc = cb; int t16 = 0;
    for (int r = tstar * 256; r < 65536; ++r) {
      u32 cnt = h[65535 - r];
      if ((int)(cc + cnt) >= target) { t16 = 65535 - r; break; }
      cc += cnt;
    }
    info[8 + b] = (info[b] << 16) | (u32)t16;          /* threshold key */
  }
}

/* ---------- 5. compact candidates (key >= T) into per-bucket lists ---------- */
__global__ void k_compact(const float* __restrict__ scores, const u32* __restrict__ info,
                          u32* __restrict__ bcnt, u64* __restrict__ cand) {
  int t = blockIdx.x * blockDim.x + threadIdx.x;
  int b = t >> 17;
  int e = t & (ANUM - 1);
  int bucket = (blockIdx.x >> 3) & (NBUCK - 1);        /* 8 consecutive blocks/bucket */
  u32 key = score_key(scores[t]);
  if (key >= info[8 + b]) {
    u32 pos = atomicAdd(&bcnt[(u32)((b << 6) + bucket) * 16u], 1u);
    if (pos < BCAP) cand[(size_t)((b << 6) + bucket) * BCAP + pos] = ((u64)key << 32) | (u32)(~(u32)e);
  }
}

/* ---------- 6. gather buckets + bitonic sort (descending), emit order+scores ---------- */
__global__ __launch_bounds__(1024) void k_sort(const u64* __restrict__ cand,
                                               const u32* __restrict__ bcnt,
                                               u32* __restrict__ order,
                                               float* __restrict__ scoresel) {
  int b = blockIdx.x, tid = threadIdx.x;
  __shared__ u64 s[CAP];
  __shared__ u32 pref[NBUCK + 1];
  if (tid < NBUCK) {                                   /* wave 0: scan bucket counts */
    u32 c = bcnt[(u32)((b << 6) + tid) * 16u];
    if (c > BCAP) c = BCAP;
    u32 inc = c;
#pragma unroll
    for (int d = 1; d < 64; d <<= 1) {
      u32 v = __shfl_up(inc, d);
      if (tid >= d) inc += v;
    }
    pref[tid + 1] = inc;
    if (tid == 0) pref[0] = 0;
  }
  __syncthreads();
  for (int i = tid; i < CAP; i += 1024) s[i] = 0ull;   /* zero pads sort below real keys */
  __syncthreads();
  for (int j = tid; j < NBUCK * BCAP; j += 1024) {
    int bk = j >> 8, sl = j & (BCAP - 1);
    u32 c = pref[bk + 1] - pref[bk];
    if ((u32)sl < c) s[pref[bk] + sl] = cand[(size_t)((b << 6) + bk) * BCAP + sl];
  }
  __syncthreads();
  for (int k = 2; k <= CAP; k <<= 1) {
    for (int j = k >> 1; j > 0; j >>= 1) {
      for (int i = tid; i < CAP; i += 1024) {
        int ixj = i ^ j;
        if (ixj > i) {
          u64 a = s[i], c = s[ixj];
          bool up = ((i & k) == 0);                     /* descending overall */
          if (up ? (a < c) : (a > c)) { s[i] = c; s[ixj] = a; }
        }
      }
      __syncthreads();
    }
  }
  for (int i = tid; i < PRE; i += 1024) {
    u64 kv = s[i];
    u32 key = (u32)(kv >> 32);
    u32 e = ~((u32)kv);
    order[b * PRE + i] = e;
    u32 u = (key & 0x80000000u) ? (key ^ 0x80000000u) : ~key;
    scoresel[b * PRE + i] = __uint_as_float(u);
  }
}

/* ---------- 7. gather + box regression (no FMA contraction: match numpy) ---------- */
__global__ void k_regress(const float* __restrict__ anchors, const float* __restrict__ deltas,
                          const u32* __restrict__ order, float* __restrict__ boxes) {
  int t = blockIdx.x * blockDim.x + threadIdx.x;
  if (t >= BATCH * PRE) return;
  int b = t / PRE;
  u32 a = order[t];
  const float* an = anchors + (size_t)a * 6;
  const float* de = deltas + ((size_t)b * ANUM + a) * 6;
  float* out = boxes + (size_t)t * 6;
#pragma unroll
  for (int d = 0; d < 3; ++d) {
    float lo = an[d], hi = an[3 + d];
    float dims = __fsub_rn(hi, lo);
    float ctr = __fadd_rn(lo, __fmul_rn(0.5f, dims));
    ctr = __fadd_rn(ctr, __fmul_rn(de[d], dims));
    float nd = __fmul_rn(dims, expf(de[3 + d]));
    float h = __fmul_rn(0.5f, nd);
    out[d] = __fsub_rn(ctr, h);
    out[3 + d] = __fadd_rn(ctr, h);
  }
}

/* ---------- 8. suppression bitmask matrix (row-major, MROW-padded) ---------- */
__global__ void k_mask(const float* __restrict__ boxes, u64* __restrict__ masks) {
  int jblk = blockIdx.x, iblk = blockIdx.y, b = blockIdx.z;
  int tid = threadIdx.x;                                /* 64 */
  __shared__ float cb[64][7];                           /* col boxes + volume */
  int j0 = jblk * 64;
  {
    int jj = j0 + tid; if (jj > PRE - 1) jj = PRE - 1;
    const float* src = boxes + ((size_t)b * PRE + jj) * 6;
#pragma unroll
    for (int d = 0; d < 6; ++d) cb[tid][d] = src[d];
    float dx = fmaxf(__fsub_rn(cb[tid][3], cb[tid][0]), 0.0f);
    float dy = fmaxf(__fsub_rn(cb[tid][4], cb[tid][1]), 0.0f);
    float dz = fmaxf(__fsub_rn(cb[tid][5], cb[tid][2]), 0.0f);
    cb[tid][6] = __fmul_rn(__fmul_rn(dx, dy), dz);
  }
  __syncthreads();
  int i = iblk * 64 + tid;
  if (i >= PRE) return;
  u64 bits = 0;
  if (j0 + 63 > i) {
    const float* rb = boxes + ((size_t)b * PRE + i) * 6;
    float l0 = rb[0], l1 = rb[1], l2 = rb[2], h0 = rb[3], h1 = rb[4], h2 = rb[5];
    float dx = fmaxf(__fsub_rn(h0, l0), 0.0f);
    float dy = fmaxf(__fsub_rn(h1, l1), 0.0f);
    float dz = fmaxf(__fsub_rn(h2, l2), 0.0f);
    float vi = __fmul_rn(__fmul_rn(dx, dy), dz);
    for (int c = 0; c < 64; ++c) {
      int j = j0 + c;
      if (j > i && j < PRE) {
        float ix = fmaxf(__fsub_rn(fminf(h0, cb[c][3]), fmaxf(l0, cb[c][0])), 0.0f);
        float iy = fmaxf(__fsub_rn(fminf(h1, cb[c][4]), fmaxf(l1, cb[c][1])), 0.0f);
        float iz = fmaxf(__fsub_rn(fminf(h2, cb[c][5]), fmaxf(l2, cb[c][2])), 0.0f);
        float iv = __fmul_rn(__fmul_rn(ix, iy), iz);
        float un = fmaxf(__fsub_rn(__fadd_rn(vi, cb[c][6]), iv), 1e-8f);
        float iou = __fdiv_rn(iv, un);
        if (iou > 0.7f) bits |= (1ull << c);
      }
    }
  }
  masks[((size_t)b * PRE + i) * MROW + jblk] = bits;
}

/* ---------- 9. chunked NMS scan: LDS-DMA stripes + scalar resolve ----------
 * Per 64-box chunk c:
 *  - 24KB stripe (64 rows x 48 u64) DMA'd into LDS with global_load_lds x24
 *    (double-buffered; counted vmcnt(24) keeps next stripe in flight)
 *  - intra resolve: pure-SGPR serial chain (readlane-sourced), ~2cyc/step
 *  - propagation: ds_read_b64 from LDS, predicated OR into per-lane rem
 */
__global__ __launch_bounds__(64) void k_scan(const u64* __restrict__ masks,
                                             u32* __restrict__ kept,
                                             u32* __restrict__ info) {
  __shared__ u64 stripe[2][64 * MROW];                  /* 2 x 24KB */
  int b = blockIdx.x;
  int lane = threadIdx.x;                               /* 64 */
  const char* Mb = (const char*)masks + (size_t)b * PRE * MROW * 8;
  int wl = lane < NW ? lane : NW - 1;
  u64 rem = 0;                                          /* lane w: removed bits of chunk w */
  int cnt = 0;

  /* chunk 0 stripe */
  {
    const char* src = Mb;
    char* dst = (char*)&stripe[0][0];
#pragma unroll
    for (int t = 0; t < 24; ++t) {
      __builtin_amdgcn_global_load_lds(
          (const __attribute__((address_space(1))) void*)(src + t * 1024 + lane * 16),
          (__attribute__((address_space(3))) void*)(dst + t * 1024 + lane * 16),
          16, 0, 0);
    }
  }

  for (int c = 0; c < NW; ++c) {
    int base = c * 64;
    int nrow = (base + 64 <= PRE) ? 64 : (PRE - base);

    if (c + 1 < NW) {
      /* issue next stripe, then wait for current (24 newest stay in flight) */
      const char* src = Mb + (size_t)(c + 1) * 64 * MROW * 8;
      char* dst = (char*)&stripe[(c + 1) & 1][0];
#pragma unroll
      for (int t = 0; t < 24; ++t) {
        __builtin_amdgcn_global_load_lds(
            (const __attribute__((address_space(1))) void*)(src + t * 1024 + lane * 16),
            (__attribute__((address_space(3))) void*)(dst + t * 1024 + lane * 16),
            16, 0, 0);
      }
      asm volatile("s_waitcnt vmcnt(24)" ::: "memory");
    } else {
      asm volatile("s_waitcnt vmcnt(0)" ::: "memory");
    }

    const u64* S = &stripe[c & 1][0];

    /* intra word: lane k holds row k's word c */
    u64 myrow = S[lane * MROW + c];

    /* alive0 = ~rem[word c] (scalar via readlane), clipped to valid rows */
    u32 alo = ~(u32)__builtin_amdgcn_readlane((int)(u32)rem, c);
    u32 ahi = ~(u32)__builtin_amdgcn_readlane((int)(u32)(rem >> 32), c);
    u64 alive = (((u64)ahi << 32) | (u64)alo);
    if (nrow < 64) alive &= ((1ull << nrow) - 1ull);

    /* serial intra-chunk resolution — SALU chain (alive is wave-uniform) */
    u32 ilo = (u32)myrow, ihi = (u32)(myrow >> 32);
#pragma unroll
    for (int k = 0; k < 64; ++k) {
      u32 rl = (u32)__builtin_amdgcn_readlane((int)ilo, k);
      u32 rh = (u32)__builtin_amdgcn_readlane((int)ihi, k);
      u64 rw = ((u64)rh << 32) | (u64)rl;
      alive &= ~(((alive >> k) & 1ull) ? rw : 0ull);
    }

    /* emit kept indices in ascending order */
    u64 ltmask = (lane == 0) ? 0ull : (~0ull >> (64 - lane));
    int pos = __popcll(alive & ltmask);
    if ((alive >> lane) & 1ull) kept[b * PRE + cnt + pos] = (u32)(base + lane);
    cnt += (int)__popcll(alive);

    /* propagate suppression of kept rows to all future chunks (from LDS) */
#pragma unroll
    for (int k = 0; k < 64; ++k) {
      u64 rv = S[k * MROW + wl];
      rem |= (((alive >> k) & 1ull) ? rv : 0ull);
    }
  }
  if (lane == 0) info[16 + b] = (u32)cnt;
}

/* ---------- 10. output assembly ---------- */
__global__ void k_out(const float* __restrict__ boxes, const float* __restrict__ scoresel,
                      const u32* __restrict__ kept, const u32* __restrict__ info,
                      float* __restrict__ out) {
  int b = blockIdx.x, tid = threadIdx.x;                /* 256 */
  int cnt = (int)info[16 + b]; if (cnt > MAXOUT) cnt = MAXOUT;
  for (int k = tid; k < MAXOUT; k += 256) {
    float pr[6] = {0.f, 0.f, 0.f, 0.f, 0.f, 0.f};
    float s = 0.f, v = 0.f;
    if (k < cnt) {
      u32 i = kept[b * PRE + k];
      const float* bx = boxes + ((size_t)b * PRE + i) * 6;
#pragma unroll
      for (int d = 0; d < 6; ++d) pr[d] = bx[d];
      s = scoresel[b * PRE + i];
      v = 1.f;
    }
    float* pp = out + ((size_t)(b * MAXOUT + k)) * 6;
#pragma unroll
    for (int d = 0; d < 6; ++d) pp[d] = pr[d];
    out[BATCH * MAXOUT * 6 + b * MAXOUT + k] = s;
    out[BATCH * MAXOUT * 7 + b * MAXOUT + k] = (float)b;
    out[BATCH * MAXOUT * 8 + b * MAXOUT + k] = v;
  }
}

extern "C" void kernel_launch(void* const* d_in, const int* in_sizes, int n_in,
                              void* d_out, int out_size, void* d_ws, size_t ws_size,
                              hipStream_t stream) {
  const float* anchors = (const float*)d_in[0];
  const float* scores  = (const float*)d_in[1];
  const float* deltas  = (const float*)d_in[2];
  float* out = (float*)d_out;

  char* w = (char*)d_ws;
  u32* hist1   = (u32*)(w + OFF_HIST1);
  u32* hist2   = (u32*)(w + OFF_HIST2);
  u32* info    = (u32*)(w + OFF_INFO);
  u32* bcnt    = (u32*)(w + OFF_BCNT);
  u64* cand    = (u64*)(w + OFF_CAND);
  u32* order   = (u32*)(w + OFF_ORDER);
  float* scoresel = (float*)(w + OFF_SCORE);
  float* boxes = (float*)(w + OFF_BOXES);
  u64* masks   = (u64*)(w + OFF_MASKS);
  u32* kept    = (u32*)(w + OFF_KEPT);

  hipMemsetAsync(d_ws, 0, MEMSET_BYTES, stream);

  int nElem = BATCH * ANUM;
  k_hist1<<<nElem / 256, 256, 0, stream>>>(scores, hist1);
  k_sel1<<<BATCH, 256, 0, stream>>>(hist1, info);
  k_hist2<<<nElem / 256, 256, 0, stream>>>(scores, info, hist2);
  k_sel2<<<BATCH, 256, 0, stream>>>(hist2, info);
  k_compact<<<nElem / 256, 256, 0, stream>>>(scores, info, bcnt, cand);
  k_sort<<<BATCH, 1024, 0, stream>>>(cand, bcnt, order, scoresel);
  k_regress<<<(BATCH * PRE + 255) / 256, 256, 0, stream>>>(anchors, deltas, order, boxes);
  k_mask<<<dim3(NW, NW, BATCH), 64, 0, stream>>>(boxes, masks);
  k_scan<<<BATCH, 64, 0, stream>>>(masks, kept, info);
  k_out<<<BATCH, 256, 0, stream>>>(boxes, scoresel, kept, info, out);
}

// Round 5
// 361.911 us; speedup vs baseline: 1.0610x; 1.0610x over previous
//
#include <hip/hip_runtime.h>
#include <hip/hip_bf16.h>
#include <cstdint>

typedef unsigned int u32;
typedef unsigned long long u64;

#define ANUM 131072
#define BATCH 4
#define PRE 3000
#define CAP 4096
#define NW 47          /* ceil(3000/64) */
#define MROW 48        /* padded u64 words per mask row */
#define MAXOUT 1000
#define NBUCK 64       /* candidate buckets per batch */
#define BCAP 256       /* slots per bucket */

/* ---- workspace layout (bytes) ----
 * cand aliases hist1 (dead after k_sel1); diag aliases hist2 (dead after k_sel2)
 */
#define OFF_CAND  0ul                  /* u64[B][NBUCK][BCAP] = 512KB (aliases hist1) */
#define OFF_HIST1 0ul                  /* u32[B][65536] = 1MB */
#define OFF_HIST2 1048576ul            /* u32[B][65536] = 1MB */
#define OFF_DIAG  1048576ul            /* u64[B][NW][64] = 96256 (aliases hist2) */
#define OFF_INFO  2097152ul            /* u32[256] */
#define OFF_BCNT  2098176ul            /* u32[B*NBUCK*16] (64B-padded counters) */
#define OFF_ORDER 2114560ul            /* u32[B][PRE] */
#define OFF_SCORE 2162560ul            /* f32[B][PRE] */
#define OFF_BOXES 2210560ul            /* f32[B][PRE][6] */
#define OFF_MASKS 2498560ul            /* u64[B][PRE][MROW] = 4608000 */
#define OFF_KEPT  7106560ul            /* u32[B][PRE] -> end 7154560 */
#define MEMSET_BYTES 2114560ul         /* hists + info + bcnt */

__device__ __forceinline__ u32 score_key(float f) {
  u32 u = __float_as_uint(f);
  return (u & 0x80000000u) ? ~u : (u | 0x80000000u);
}

/* ---------- 1. histogram of top 16 bits ---------- */
__global__ void k_hist1(const float* __restrict__ scores, u32* __restrict__ hist) {
  int t = blockIdx.x * blockDim.x + threadIdx.x;
  int b = t >> 17;
  u32 key = score_key(scores[t]);
  atomicAdd(&hist[(b << 16) + (key >> 16)], 1u);
}

/* ---------- 2. find high-16 bin crossing rank 3000 ---------- */
__global__ void k_sel1(const u32* __restrict__ hist, u32* __restrict__ info) {
  int b = blockIdx.x, tid = threadIdx.x;              /* 256 threads */
  __shared__ u32 part[256];
  const u32* h = hist + (b << 16);
  u32 s = 0;
  for (int r = tid * 256; r < tid * 256 + 256; ++r) s += h[65535 - r];
  part[tid] = s;
  __syncthreads();
  if (tid == 0) {
    u32 c = 0; int tstar = 0; u32 cb = 0;
    for (int t = 0; t < 256; ++t) {
      if (c + part[t] >= PRE) { tstar = t; cb = c; break; }
      c += part[t];
    }
    u32 cc = cb; int b16 = 0;
    for (int r = tstar * 256; r < 65536; ++r) {
      u32 cnt = h[65535 - r];
      if (cc + cnt >= PRE) { b16 = 65535 - r; break; }
      cc += cnt;
    }
    info[b] = (u32)b16;
    info[4 + b] = cc;
  }
}

/* ---------- 3. histogram of low 16 bits within the boundary bin ---------- */
__global__ void k_hist2(const float* __restrict__ scores, const u32* __restrict__ info,
                        u32* __restrict__ hist2) {
  int t = blockIdx.x * blockDim.x + threadIdx.x;
  int b = t >> 17;
  u32 key = score_key(scores[t]);
  if ((key >> 16) == info[b])
    atomicAdd(&hist2[(b << 16) + (key & 0xFFFFu)], 1u);
}

/* ---------- 4. exact threshold key T ---------- */
__global__ void k_sel2(const u32* __restrict__ hist2, u32* __restrict__ info) {
  int b = blockIdx.x, tid = threadIdx.x;
  __shared__ u32 part[256];
  const u32* h = hist2 + (b << 16);
  u32 s = 0;
  for (int r = tid * 256; r < tid * 256 + 256; ++r) s += h[65535 - r];
  part[tid] = s;
  __syncthreads();
  if (tid == 0) {
    int target = PRE - (int)info[4 + b];
    u32 c = 0; int tstar = 0; u32 cb = 0;
    for (int t = 0; t < 256; ++t) {
      if ((int)(c + part[t]) >= target) { tstar = t; cb = c; break; }
      c += part[t];
    }
    u32 cc = cb; int t16 = 0;
    for (int r = tstar * 256; r < 65536; ++r) {
      u32 cnt = h[65535 - r];
      if ((int)(cc + cnt) >= target) { t16 = 65535 - r; break; }
      cc += cnt;
    }
    info[8 + b] = (info[b] << 16) | (u32)t16;
  }
}

/* ---------- 5. compact candidates (key >= T) into per-bucket lists ---------- */
__global__ void k_compact(const float* __restrict__ scores, const u32* __restrict__ info,
                          u32* __restrict__ bcnt, u64* __restrict__ cand) {
  int t = blockIdx.x * blockDim.x + threadIdx.x;
  int b = t >> 17;
  int e = t & (ANUM - 1);
  int bucket = (blockIdx.x >> 3) & (NBUCK - 1);
  u32 key = score_key(scores[t]);
  if (key >= info[8 + b]) {
    u32 pos = atomicAdd(&bcnt[(u32)((b << 6) + bucket) * 16u], 1u);
    if (pos < BCAP) cand[(size_t)((b << 6) + bucket) * BCAP + pos] = ((u64)key << 32) | (u32)(~(u32)e);
  }
}

/* ---------- 6. gather buckets + bitonic sort (descending) ---------- */
__global__ __launch_bounds__(1024) void k_sort(const u64* __restrict__ cand,
                                               const u32* __restrict__ bcnt,
                                               u32* __restrict__ order,
                                               float* __restrict__ scoresel) {
  int b = blockIdx.x, tid = threadIdx.x;
  __shared__ u64 s[CAP];
  __shared__ u32 pref[NBUCK + 1];
  if (tid < NBUCK) {
    u32 c = bcnt[(u32)((b << 6) + tid) * 16u];
    if (c > BCAP) c = BCAP;
    u32 inc = c;
#pragma unroll
    for (int d = 1; d < 64; d <<= 1) {
      u32 v = __shfl_up(inc, d);
      if (tid >= d) inc += v;
    }
    pref[tid + 1] = inc;
    if (tid == 0) pref[0] = 0;
  }
  __syncthreads();
  for (int i = tid; i < CAP; i += 1024) s[i] = 0ull;
  __syncthreads();
  for (int j = tid; j < NBUCK * BCAP; j += 1024) {
    int bk = j >> 8, sl = j & (BCAP - 1);
    u32 c = pref[bk + 1] - pref[bk];
    if ((u32)sl < c) s[pref[bk] + sl] = cand[(size_t)((b << 6) + bk) * BCAP + sl];
  }
  __syncthreads();
  for (int k = 2; k <= CAP; k <<= 1) {
    for (int j = k >> 1; j > 0; j >>= 1) {
      for (int i = tid; i < CAP; i += 1024) {
        int ixj = i ^ j;
        if (ixj > i) {
          u64 a = s[i], c = s[ixj];
          bool up = ((i & k) == 0);
          if (up ? (a < c) : (a > c)) { s[i] = c; s[ixj] = a; }
        }
      }
      __syncthreads();
    }
  }
  for (int i = tid; i < PRE; i += 1024) {
    u64 kv = s[i];
    u32 key = (u32)(kv >> 32);
    u32 e = ~((u32)kv);
    order[b * PRE + i] = e;
    u32 u = (key & 0x80000000u) ? (key ^ 0x80000000u) : ~key;
    scoresel[b * PRE + i] = __uint_as_float(u);
  }
}

/* ---------- 7. gather + box regression ---------- */
__global__ void k_regress(const float* __restrict__ anchors, const float* __restrict__ deltas,
                          const u32* __restrict__ order, float* __restrict__ boxes) {
  int t = blockIdx.x * blockDim.x + threadIdx.x;
  if (t >= BATCH * PRE) return;
  int b = t / PRE;
  u32 a = order[t];
  const float* an = anchors + (size_t)a * 6;
  const float* de = deltas + ((size_t)b * ANUM + a) * 6;
  float* out = boxes + (size_t)t * 6;
#pragma unroll
  for (int d = 0; d < 3; ++d) {
    float lo = an[d], hi = an[3 + d];
    float dims = __fsub_rn(hi, lo);
    float ctr = __fadd_rn(lo, __fmul_rn(0.5f, dims));
    ctr = __fadd_rn(ctr, __fmul_rn(de[d], dims));
    float nd = __fmul_rn(dims, expf(de[3 + d]));
    float h = __fmul_rn(0.5f, nd);
    out[d] = __fsub_rn(ctr, h);
    out[3 + d] = __fadd_rn(ctr, h);
  }
}

/* ---------- 8. suppression bitmask matrix (+ diag blocks) ---------- */
__global__ void k_mask(const float* __restrict__ boxes, u64* __restrict__ masks,
                       u64* __restrict__ diag) {
  int jblk = blockIdx.x, iblk = blockIdx.y, b = blockIdx.z;
  int tid = threadIdx.x;                                /* 64 */
  __shared__ float cb[64][7];
  int j0 = jblk * 64;
  {
    int jj = j0 + tid; if (jj > PRE - 1) jj = PRE - 1;
    const float* src = boxes + ((size_t)b * PRE + jj) * 6;
#pragma unroll
    for (int d = 0; d < 6; ++d) cb[tid][d] = src[d];
    float dx = fmaxf(__fsub_rn(cb[tid][3], cb[tid][0]), 0.0f);
    float dy = fmaxf(__fsub_rn(cb[tid][4], cb[tid][1]), 0.0f);
    float dz = fmaxf(__fsub_rn(cb[tid][5], cb[tid][2]), 0.0f);
    cb[tid][6] = __fmul_rn(__fmul_rn(dx, dy), dz);
  }
  __syncthreads();
  int i = iblk * 64 + tid;
  if (i >= PRE) return;
  u64 bits = 0;
  if (j0 + 63 > i) {
    const float* rb = boxes + ((size_t)b * PRE + i) * 6;
    float l0 = rb[0], l1 = rb[1], l2 = rb[2], h0 = rb[3], h1 = rb[4], h2 = rb[5];
    float dx = fmaxf(__fsub_rn(h0, l0), 0.0f);
    float dy = fmaxf(__fsub_rn(h1, l1), 0.0f);
    float dz = fmaxf(__fsub_rn(h2, l2), 0.0f);
    float vi = __fmul_rn(__fmul_rn(dx, dy), dz);
    for (int c = 0; c < 64; ++c) {
      int j = j0 + c;
      if (j > i && j < PRE) {
        float ix = fmaxf(__fsub_rn(fminf(h0, cb[c][3]), fmaxf(l0, cb[c][0])), 0.0f);
        float iy = fmaxf(__fsub_rn(fminf(h1, cb[c][4]), fmaxf(l1, cb[c][1])), 0.0f);
        float iz = fmaxf(__fsub_rn(fminf(h2, cb[c][5]), fmaxf(l2, cb[c][2])), 0.0f);
        float iv = __fmul_rn(__fmul_rn(ix, iy), iz);
        float un = fmaxf(__fsub_rn(__fadd_rn(vi, cb[c][6]), iv), 1e-8f);
        float iou = __fdiv_rn(iv, un);
        if (iou > 0.7f) bits |= (1ull << c);
      }
    }
  }
  masks[((size_t)b * PRE + i) * MROW + jblk] = bits;
  if (iblk == jblk) diag[((size_t)b * NW + jblk) * 64 + tid] = bits;
}

/* ---------- 9. cooperative 8-wave NMS scan ----------
 * Per 64-box chunk: all waves redundantly resolve intra-chunk (SALU chain on
 * readfirstlane'd scalar alive; readlane row extraction off-chain); wave g
 * propagates its 8 rows (VGPR double-buffered, static addrs -> latency hidden)
 * into LDS rem[] via u32 atomicOr. One barrier per chunk (writers touch
 * lanes > c, reader reads index c -> disjoint).
 */
__global__ __launch_bounds__(512) void k_scan(const u64* __restrict__ masks,
                                              const u64* __restrict__ diag,
                                              u32* __restrict__ kept,
                                              u32* __restrict__ info) {
  __shared__ u32 remL[NW][2];
  int b = blockIdx.x;
  int tid = threadIdx.x;
  int lane = tid & 63, wid = tid >> 6;                  /* 8 waves */
  const u64* Mb = masks + (size_t)b * PRE * MROW;
  const u64* Db = diag + (size_t)b * NW * 64;
  int wl = lane < NW ? lane : NW - 1;
  int k0 = wid * 8;
  if (tid < NW) { remL[tid][0] = 0u; remL[tid][1] = 0u; }

  u64 cur[8], nxt[8], dcur, dnxt;
#pragma unroll
  for (int j = 0; j < 8; ++j) {
    int rk = k0 + j; if (rk > PRE - 1) rk = PRE - 1;
    cur[j] = Mb[(size_t)rk * MROW + wl];
  }
  dcur = Db[lane];
  __syncthreads();

  int cnt = 0;
  for (int c = 0; c < NW; ++c) {
    int base = c * 64;
    int nrow = (base + 64 <= PRE) ? 64 : (PRE - base);

    if (c + 1 < NW) {                                   /* prefetch next chunk */
      int nb = base + 64;
#pragma unroll
      for (int j = 0; j < 8; ++j) {
        int rk = nb + k0 + j; if (rk > PRE - 1) rk = PRE - 1;
        nxt[j] = Mb[(size_t)rk * MROW + wl];
      }
      dnxt = Db[(size_t)(c + 1) * 64 + lane];
    }

    /* alive0 from LDS rem word c (scalar) */
    u32 r0 = remL[c][0], r1 = remL[c][1];
    u32 alo = __builtin_amdgcn_readfirstlane((int)~r0);
    u32 ahi = __builtin_amdgcn_readfirstlane((int)~r1);
    u64 alive = (((u64)ahi << 32) | (u64)alo);
    if (nrow < 64) alive &= ((1ull << nrow) - 1ull);

    /* serial intra-chunk resolve: SALU chain, readlanes off-chain */
    u32 ilo = (u32)dcur, ihi = (u32)(dcur >> 32);
#pragma unroll
    for (int k = 0; k < 64; ++k) {
      u32 rl = (u32)__builtin_amdgcn_readlane((int)ilo, k);
      u32 rh = (u32)__builtin_amdgcn_readlane((int)ihi, k);
      u64 rw = ((u64)rh << 32) | (u64)rl;
      alive &= ~(((alive >> k) & 1ull) ? rw : 0ull);
    }

    /* emit kept indices (wave 0) */
    if (wid == 0) {
      u64 ltmask = (lane == 0) ? 0ull : (~0ull >> (64 - lane));
      int pos = __popcll(alive & ltmask);
      if ((alive >> lane) & 1ull) kept[b * PRE + cnt + pos] = (u32)(base + lane);
    }
    cnt += (int)__popcll(alive);

    /* propagate this wave's kept rows into future rem words */
    u64 acc = 0;
#pragma unroll
    for (int j = 0; j < 8; ++j)
      acc |= (((alive >> (k0 + j)) & 1ull) ? cur[j] : 0ull);
    if (lane > c && lane < NW && acc) {
      atomicOr(&remL[lane][0], (u32)acc);
      atomicOr(&remL[lane][1], (u32)(acc >> 32));
    }
    __syncthreads();

#pragma unroll
    for (int j = 0; j < 8; ++j) cur[j] = nxt[j];
    dcur = dnxt;
  }
  if (tid == 0) info[16 + b] = (u32)cnt;
}

/* ---------- 10. output assembly ---------- */
__global__ void k_out(const float* __restrict__ boxes, const float* __restrict__ scoresel,
                      const u32* __restrict__ kept, const u32* __restrict__ info,
                      float* __restrict__ out) {
  int b = blockIdx.x, tid = threadIdx.x;                /* 256 */
  int cnt = (int)info[16 + b]; if (cnt > MAXOUT) cnt = MAXOUT;
  for (int k = tid; k < MAXOUT; k += 256) {
    float pr[6] = {0.f, 0.f, 0.f, 0.f, 0.f, 0.f};
    float s = 0.f, v = 0.f;
    if (k < cnt) {
      u32 i = kept[b * PRE + k];
      const float* bx = boxes + ((size_t)b * PRE + i) * 6;
#pragma unroll
      for (int d = 0; d < 6; ++d) pr[d] = bx[d];
      s = scoresel[b * PRE + i];
      v = 1.f;
    }
    float* pp = out + ((size_t)(b * MAXOUT + k)) * 6;
#pragma unroll
    for (int d = 0; d < 6; ++d) pp[d] = pr[d];
    out[BATCH * MAXOUT * 6 + b * MAXOUT + k] = s;
    out[BATCH * MAXOUT * 7 + b * MAXOUT + k] = (float)b;
    out[BATCH * MAXOUT * 8 + b * MAXOUT + k] = v;
  }
}

extern "C" void kernel_launch(void* const* d_in, const int* in_sizes, int n_in,
                              void* d_out, int out_size, void* d_ws, size_t ws_size,
                              hipStream_t stream) {
  const float* anchors = (const float*)d_in[0];
  const float* scores  = (const float*)d_in[1];
  const float* deltas  = (const float*)d_in[2];
  float* out = (float*)d_out;

  char* w = (char*)d_ws;
  u32* hist1   = (u32*)(w + OFF_HIST1);
  u32* hist2   = (u32*)(w + OFF_HIST2);
  u64* diag    = (u64*)(w + OFF_DIAG);
  u32* info    = (u32*)(w + OFF_INFO);
  u32* bcnt    = (u32*)(w + OFF_BCNT);
  u64* cand    = (u64*)(w + OFF_CAND);
  u32* order   = (u32*)(w + OFF_ORDER);
  float* scoresel = (float*)(w + OFF_SCORE);
  float* boxes = (float*)(w + OFF_BOXES);
  u64* masks   = (u64*)(w + OFF_MASKS);
  u32* kept    = (u32*)(w + OFF_KEPT);

  hipMemsetAsync(d_ws, 0, MEMSET_BYTES, stream);

  int nElem = BATCH * ANUM;
  k_hist1<<<nElem / 256, 256, 0, stream>>>(scores, hist1);
  k_sel1<<<BATCH, 256, 0, stream>>>(hist1, info);
  k_hist2<<<nElem / 256, 256, 0, stream>>>(scores, info, hist2);
  k_sel2<<<BATCH, 256, 0, stream>>>(hist2, info);
  k_compact<<<nElem / 256, 256, 0, stream>>>(scores, info, bcnt, cand);
  k_sort<<<BATCH, 1024, 0, stream>>>(cand, bcnt, order, scoresel);
  k_regress<<<(BATCH * PRE + 255) / 256, 256, 0, stream>>>(anchors, deltas, order, boxes);
  k_mask<<<dim3(NW, NW, BATCH), 64, 0, stream>>>(boxes, masks, diag);
  k_scan<<<BATCH, 512, 0, stream>>>(masks, diag, kept, info);
  k_out<<<BATCH, 256, 0, stream>>>(boxes, scoresel, kept, info, out);
}

// Round 6
// 355.223 us; speedup vs baseline: 1.0810x; 1.0188x over previous
//
#include <hip/hip_runtime.h>
#include <hip/hip_bf16.h>
#include <cstdint>

typedef unsigned int u32;
typedef unsigned long long u64;

#define ANUM 131072
#define BATCH 4
#define PRE 3000
#define CAP 4096
#define NW 47          /* ceil(3000/64) */
#define MROW 48        /* padded u64 words per mask row */
#define MAXOUT 1000
#define NBUCK 64       /* candidate buckets per batch */
#define BCAP 256       /* slots per bucket */

/* ---- workspace layout (bytes) ----
 * cand aliases hist1 (dead after k_sel1); diag aliases hist2 (dead after k_sel2)
 */
#define OFF_CAND  0ul                  /* u64[B][NBUCK][BCAP] = 512KB (aliases hist1) */
#define OFF_HIST1 0ul                  /* u32[B][65536] = 1MB */
#define OFF_HIST2 1048576ul            /* u32[B][65536] = 1MB */
#define OFF_DIAG  1048576ul            /* u64[B][NW][64] = 96256 (aliases hist2) */
#define OFF_INFO  2097152ul            /* u32[256] */
#define OFF_BCNT  2098176ul            /* u32[B*NBUCK*16] (64B-padded counters) */
#define OFF_ORDER 2114560ul            /* u32[B][PRE] */
#define OFF_SCORE 2162560ul            /* f32[B][PRE] */
#define OFF_BOXES 2210560ul            /* f32[B][PRE][6] */
#define OFF_MASKS 2498560ul            /* u64[B][PRE][MROW] = 4608000 */
#define OFF_KEPT  7106560ul            /* u32[B][PRE] -> end 7154560 */
#define MEMSET_BYTES 2114560ul         /* hists + info + bcnt */

__device__ __forceinline__ u32 score_key(float f) {
  u32 u = __float_as_uint(f);
  return (u & 0x80000000u) ? ~u : (u | 0x80000000u);
}

/* ---------- 1. histogram of top 16 bits ---------- */
__global__ void k_hist1(const float* __restrict__ scores, u32* __restrict__ hist) {
  int t = blockIdx.x * blockDim.x + threadIdx.x;
  int b = t >> 17;
  u32 key = score_key(scores[t]);
  atomicAdd(&hist[(b << 16) + (key >> 16)], 1u);
}

/* ---------- 2. find high-16 bin crossing rank 3000 ---------- */
__global__ void k_sel1(const u32* __restrict__ hist, u32* __restrict__ info) {
  int b = blockIdx.x, tid = threadIdx.x;              /* 256 threads */
  __shared__ u32 part[256];
  const u32* h = hist + (b << 16);
  u32 s = 0;
  for (int r = tid * 256; r < tid * 256 + 256; ++r) s += h[65535 - r];
  part[tid] = s;
  __syncthreads();
  if (tid == 0) {
    u32 c = 0; int tstar = 0; u32 cb = 0;
    for (int t = 0; t < 256; ++t) {
      if (c + part[t] >= PRE) { tstar = t; cb = c; break; }
      c += part[t];
    }
    u32 cc = cb; int b16 = 0;
    for (int r = tstar * 256; r < 65536; ++r) {
      u32 cnt = h[65535 - r];
      if (cc + cnt >= PRE) { b16 = 65535 - r; break; }
      cc += cnt;
    }
    info[b] = (u32)b16;
    info[4 + b] = cc;
  }
}

/* ---------- 3. histogram of low 16 bits within the boundary bin ---------- */
__global__ void k_hist2(const float* __restrict__ scores, const u32* __restrict__ info,
                        u32* __restrict__ hist2) {
  int t = blockIdx.x * blockDim.x + threadIdx.x;
  int b = t >> 17;
  u32 key = score_key(scores[t]);
  if ((key >> 16) == info[b])
    atomicAdd(&hist2[(b << 16) + (key & 0xFFFFu)], 1u);
}

/* ---------- 4. exact threshold key T ---------- */
__global__ void k_sel2(const u32* __restrict__ hist2, u32* __restrict__ info) {
  int b = blockIdx.x, tid = threadIdx.x;
  __shared__ u32 part[256];
  const u32* h = hist2 + (b << 16);
  u32 s = 0;
  for (int r = tid * 256; r < tid * 256 + 256; ++r) s += h[65535 - r];
  part[tid] = s;
  __syncthreads();
  if (tid == 0) {
    int target = PRE - (int)info[4 + b];
    u32 c = 0; int tstar = 0; u32 cb = 0;
    for (int t = 0; t < 256; ++t) {
      if ((int)(c + part[t]) >= target) { tstar = t; cb = c; break; }
      c += part[t];
    }
    u32 cc = cb; int t16 = 0;
    for (int r = tstar * 256; r < 65536; ++r) {
      u32 cnt = h[65535 - r];
      if ((int)(cc + cnt) >= target) { t16 = 65535 - r; break; }
      cc += cnt;
    }
    info[8 + b] = (info[b] << 16) | (u32)t16;
  }
}

/* ---------- 5. compact candidates (key >= T) into per-bucket lists ---------- */
__global__ void k_compact(const float* __restrict__ scores, const u32* __restrict__ info,
                          u32* __restrict__ bcnt, u64* __restrict__ cand) {
  int t = blockIdx.x * blockDim.x + threadIdx.x;
  int b = t >> 17;
  int e = t & (ANUM - 1);
  int bucket = (blockIdx.x >> 3) & (NBUCK - 1);
  u32 key = score_key(scores[t]);
  if (key >= info[8 + b]) {
    u32 pos = atomicAdd(&bcnt[(u32)((b << 6) + bucket) * 16u], 1u);
    if (pos < BCAP) cand[(size_t)((b << 6) + bucket) * BCAP + pos] = ((u64)key << 32) | (u32)(~(u32)e);
  }
}

/* ---------- 6. gather buckets + bitonic sort (descending) ---------- */
__global__ __launch_bounds__(1024) void k_sort(const u64* __restrict__ cand,
                                               const u32* __restrict__ bcnt,
                                               u32* __restrict__ order,
                                               float* __restrict__ scoresel) {
  int b = blockIdx.x, tid = threadIdx.x;
  __shared__ u64 s[CAP];
  __shared__ u32 pref[NBUCK + 1];
  if (tid < NBUCK) {
    u32 c = bcnt[(u32)((b << 6) + tid) * 16u];
    if (c > BCAP) c = BCAP;
    u32 inc = c;
#pragma unroll
    for (int d = 1; d < 64; d <<= 1) {
      u32 v = __shfl_up(inc, d);
      if (tid >= d) inc += v;
    }
    pref[tid + 1] = inc;
    if (tid == 0) pref[0] = 0;
  }
  __syncthreads();
  for (int i = tid; i < CAP; i += 1024) s[i] = 0ull;
  __syncthreads();
  for (int j = tid; j < NBUCK * BCAP; j += 1024) {
    int bk = j >> 8, sl = j & (BCAP - 1);
    u32 c = pref[bk + 1] - pref[bk];
    if ((u32)sl < c) s[pref[bk] + sl] = cand[(size_t)((b << 6) + bk) * BCAP + sl];
  }
  __syncthreads();
  for (int k = 2; k <= CAP; k <<= 1) {
    for (int j = k >> 1; j > 0; j >>= 1) {
      for (int i = tid; i < CAP; i += 1024) {
        int ixj = i ^ j;
        if (ixj > i) {
          u64 a = s[i], c = s[ixj];
          bool up = ((i & k) == 0);
          if (up ? (a < c) : (a > c)) { s[i] = c; s[ixj] = a; }
        }
      }
      __syncthreads();
    }
  }
  for (int i = tid; i < PRE; i += 1024) {
    u64 kv = s[i];
    u32 key = (u32)(kv >> 32);
    u32 e = ~((u32)kv);
    order[b * PRE + i] = e;
    u32 u = (key & 0x80000000u) ? (key ^ 0x80000000u) : ~key;
    scoresel[b * PRE + i] = __uint_as_float(u);
  }
}

/* ---------- 7. gather + box regression ---------- */
__global__ void k_regress(const float* __restrict__ anchors, const float* __restrict__ deltas,
                          const u32* __restrict__ order, float* __restrict__ boxes) {
  int t = blockIdx.x * blockDim.x + threadIdx.x;
  if (t >= BATCH * PRE) return;
  int b = t / PRE;
  u32 a = order[t];
  const float* an = anchors + (size_t)a * 6;
  const float* de = deltas + ((size_t)b * ANUM + a) * 6;
  float* out = boxes + (size_t)t * 6;
#pragma unroll
  for (int d = 0; d < 3; ++d) {
    float lo = an[d], hi = an[3 + d];
    float dims = __fsub_rn(hi, lo);
    float ctr = __fadd_rn(lo, __fmul_rn(0.5f, dims));
    ctr = __fadd_rn(ctr, __fmul_rn(de[d], dims));
    float nd = __fmul_rn(dims, expf(de[3 + d]));
    float h = __fmul_rn(0.5f, nd);
    out[d] = __fsub_rn(ctr, h);
    out[3 + d] = __fadd_rn(ctr, h);
  }
}

/* ---------- 8. suppression bitmask matrix (+ diag blocks) ---------- */
__global__ void k_mask(const float* __restrict__ boxes, u64* __restrict__ masks,
                       u64* __restrict__ diag) {
  int jblk = blockIdx.x, iblk = blockIdx.y, b = blockIdx.z;
  int tid = threadIdx.x;                                /* 64 */
  __shared__ float cb[64][7];
  int j0 = jblk * 64;
  {
    int jj = j0 + tid; if (jj > PRE - 1) jj = PRE - 1;
    const float* src = boxes + ((size_t)b * PRE + jj) * 6;
#pragma unroll
    for (int d = 0; d < 6; ++d) cb[tid][d] = src[d];
    float dx = fmaxf(__fsub_rn(cb[tid][3], cb[tid][0]), 0.0f);
    float dy = fmaxf(__fsub_rn(cb[tid][4], cb[tid][1]), 0.0f);
    float dz = fmaxf(__fsub_rn(cb[tid][5], cb[tid][2]), 0.0f);
    cb[tid][6] = __fmul_rn(__fmul_rn(dx, dy), dz);
  }
  __syncthreads();
  int i = iblk * 64 + tid;
  if (i >= PRE) return;
  u64 bits = 0;
  if (j0 + 63 > i) {
    const float* rb = boxes + ((size_t)b * PRE + i) * 6;
    float l0 = rb[0], l1 = rb[1], l2 = rb[2], h0 = rb[3], h1 = rb[4], h2 = rb[5];
    float dx = fmaxf(__fsub_rn(h0, l0), 0.0f);
    float dy = fmaxf(__fsub_rn(h1, l1), 0.0f);
    float dz = fmaxf(__fsub_rn(h2, l2), 0.0f);
    float vi = __fmul_rn(__fmul_rn(dx, dy), dz);
    for (int c = 0; c < 64; ++c) {
      int j = j0 + c;
      if (j > i && j < PRE) {
        float ix = fmaxf(__fsub_rn(fminf(h0, cb[c][3]), fmaxf(l0, cb[c][0])), 0.0f);
        float iy = fmaxf(__fsub_rn(fminf(h1, cb[c][4]), fmaxf(l1, cb[c][1])), 0.0f);
        float iz = fmaxf(__fsub_rn(fminf(h2, cb[c][5]), fmaxf(l2, cb[c][2])), 0.0f);
        float iv = __fmul_rn(__fmul_rn(ix, iy), iz);
        float un = fmaxf(__fsub_rn(__fadd_rn(vi, cb[c][6]), iv), 1e-8f);
        float iou = __fdiv_rn(iv, un);
        if (iou > 0.7f) bits |= (1ull << c);
      }
    }
  }
  masks[((size_t)b * PRE + i) * MROW + jblk] = bits;
  if (iblk == jblk) diag[((size_t)b * NW + jblk) * 64 + tid] = bits;
}

/* ---------- 9. cooperative 8-wave NMS scan, single-wave resolve ----------
 * Per 64-box chunk:
 *  - wave 0 ALONE runs the serial intra-chunk resolve (SALU chain; other
 *    waves park at the barrier -> no SIMD issue contention on the chain),
 *    emits kept indices, publishes alive (2 u32) to LDS
 *  - barrier; all 8 waves propagate their 8 rows (VGPR double-buffered
 *    prefetch, static addrs) into LDS rem[] via u32 atomicOr; barrier
 */
__global__ __launch_bounds__(512) void k_scan(const u64* __restrict__ masks,
                                              const u64* __restrict__ diag,
                                              u32* __restrict__ kept,
                                              u32* __restrict__ info) {
  __shared__ u32 remL[NW][2];
  __shared__ u32 aliveL[2];
  int b = blockIdx.x;
  int tid = threadIdx.x;
  int lane = tid & 63, wid = tid >> 6;                  /* 8 waves */
  const u64* Mb = masks + (size_t)b * PRE * MROW;
  const u64* Db = diag + (size_t)b * NW * 64;
  int wl = lane < NW ? lane : NW - 1;
  int k0 = wid * 8;
  if (tid < NW) { remL[tid][0] = 0u; remL[tid][1] = 0u; }

  u64 cur[8], nxt[8], dcur = 0, dnxt = 0;
#pragma unroll
  for (int j = 0; j < 8; ++j) {
    int rk = k0 + j; if (rk > PRE - 1) rk = PRE - 1;
    cur[j] = Mb[(size_t)rk * MROW + wl];
  }
  if (wid == 0) dcur = Db[lane];
  __syncthreads();

  int cnt = 0;
  for (int c = 0; c < NW; ++c) {
    int base = c * 64;
    int nrow = (base + 64 <= PRE) ? 64 : (PRE - base);

    if (c + 1 < NW) {                                   /* prefetch next chunk */
      int nb = base + 64;
#pragma unroll
      for (int j = 0; j < 8; ++j) {
        int rk = nb + k0 + j; if (rk > PRE - 1) rk = PRE - 1;
        nxt[j] = Mb[(size_t)rk * MROW + wl];
      }
      if (wid == 0) dnxt = Db[(size_t)(c + 1) * 64 + lane];
    }

    if (wid == 0) {
      /* alive0 from LDS rem word c (scalar) */
      u32 alo = __builtin_amdgcn_readfirstlane((int)~remL[c][0]);
      u32 ahi = __builtin_amdgcn_readfirstlane((int)~remL[c][1]);
      u64 alive = (((u64)ahi << 32) | (u64)alo);
      if (nrow < 64) alive &= ((1ull << nrow) - 1ull);

      /* serial intra-chunk resolve: SALU chain, readlanes off-chain */
      u32 ilo = (u32)dcur, ihi = (u32)(dcur >> 32);
#pragma unroll
      for (int k = 0; k < 64; ++k) {
        u32 rl = (u32)__builtin_amdgcn_readlane((int)ilo, k);
        u32 rh = (u32)__builtin_amdgcn_readlane((int)ihi, k);
        u64 rw = ((u64)rh << 32) | (u64)rl;
        alive &= ~(((alive >> k) & 1ull) ? rw : 0ull);
      }

      /* emit kept indices in ascending order */
      u64 ltmask = (lane == 0) ? 0ull : (~0ull >> (64 - lane));
      int pos = __popcll(alive & ltmask);
      if ((alive >> lane) & 1ull) kept[b * PRE + cnt + pos] = (u32)(base + lane);
      cnt += (int)__popcll(alive);
      if (lane == 0) { aliveL[0] = (u32)alive; aliveL[1] = (u32)(alive >> 32); }
    }
    __syncthreads();

    /* all waves: propagate kept rows into future rem words */
    u64 alive = (((u64)aliveL[1] << 32) | (u64)aliveL[0]);
    u64 acc = 0;
#pragma unroll
    for (int j = 0; j < 8; ++j)
      acc |= (((alive >> (k0 + j)) & 1ull) ? cur[j] : 0ull);
    if (lane > c && lane < NW && acc) {
      atomicOr(&remL[lane][0], (u32)acc);
      atomicOr(&remL[lane][1], (u32)(acc >> 32));
    }
    __syncthreads();

#pragma unroll
    for (int j = 0; j < 8; ++j) cur[j] = nxt[j];
    if (wid == 0) dcur = dnxt;
  }
  if (tid == 0) info[16 + b] = (u32)cnt;
}

/* ---------- 10. output assembly ---------- */
__global__ void k_out(const float* __restrict__ boxes, const float* __restrict__ scoresel,
                      const u32* __restrict__ kept, const u32* __restrict__ info,
                      float* __restrict__ out) {
  int b = blockIdx.x, tid = threadIdx.x;                /* 256 */
  int cnt = (int)info[16 + b]; if (cnt > MAXOUT) cnt = MAXOUT;
  for (int k = tid; k < MAXOUT; k += 256) {
    float pr[6] = {0.f, 0.f, 0.f, 0.f, 0.f, 0.f};
    float s = 0.f, v = 0.f;
    if (k < cnt) {
      u32 i = kept[b * PRE + k];
      const float* bx = boxes + ((size_t)b * PRE + i) * 6;
#pragma unroll
      for (int d = 0; d < 6; ++d) pr[d] = bx[d];
      s = scoresel[b * PRE + i];
      v = 1.f;
    }
    float* pp = out + ((size_t)(b * MAXOUT + k)) * 6;
#pragma unroll
    for (int d = 0; d < 6; ++d) pp[d] = pr[d];
    out[BATCH * MAXOUT * 6 + b * MAXOUT + k] = s;
    out[BATCH * MAXOUT * 7 + b * MAXOUT + k] = (float)b;
    out[BATCH * MAXOUT * 8 + b * MAXOUT + k] = v;
  }
}

extern "C" void kernel_launch(void* const* d_in, const int* in_sizes, int n_in,
                              void* d_out, int out_size, void* d_ws, size_t ws_size,
                              hipStream_t stream) {
  const float* anchors = (const float*)d_in[0];
  const float* scores  = (const float*)d_in[1];
  const float* deltas  = (const float*)d_in[2];
  float* out = (float*)d_out;

  char* w = (char*)d_ws;
  u32* hist1   = (u32*)(w + OFF_HIST1);
  u32* hist2   = (u32*)(w + OFF_HIST2);
  u64* diag    = (u64*)(w + OFF_DIAG);
  u32* info    = (u32*)(w + OFF_INFO);
  u32* bcnt    = (u32*)(w + OFF_BCNT);
  u64* cand    = (u64*)(w + OFF_CAND);
  u32* order   = (u32*)(w + OFF_ORDER);
  float* scoresel = (float*)(w + OFF_SCORE);
  float* boxes = (float*)(w + OFF_BOXES);
  u64* masks   = (u64*)(w + OFF_MASKS);
  u32* kept    = (u32*)(w + OFF_KEPT);

  hipMemsetAsync(d_ws, 0, MEMSET_BYTES, stream);

  int nElem = BATCH * ANUM;
  k_hist1<<<nElem / 256, 256, 0, stream>>>(scores, hist1);
  k_sel1<<<BATCH, 256, 0, stream>>>(hist1, info);
  k_hist2<<<nElem / 256, 256, 0, stream>>>(scores, info, hist2);
  k_sel2<<<BATCH, 256, 0, stream>>>(hist2, info);
  k_compact<<<nElem / 256, 256, 0, stream>>>(scores, info, bcnt, cand);
  k_sort<<<BATCH, 1024, 0, stream>>>(cand, bcnt, order, scoresel);
  k_regress<<<(BATCH * PRE + 255) / 256, 256, 0, stream>>>(anchors, deltas, order, boxes);
  k_mask<<<dim3(NW, NW, BATCH), 64, 0, stream>>>(boxes, masks, diag);
  k_scan<<<BATCH, 512, 0, stream>>>(masks, diag, kept, info);
  k_out<<<BATCH, 256, 0, stream>>>(boxes, scoresel, kept, info, out);
}